// Round 6
// baseline (3124.189 us; speedup 1.0000x reference)
//
#include <hip/hip_runtime.h>
#include <stdint.h>

typedef int v4i  __attribute__((ext_vector_type(4)));
typedef int v16i __attribute__((ext_vector_type(16)));

#define M_TOK 8192
#define N_OUT 4096
#define K_IN  4096

#define BM 256
#define BN 256
#define BK 64                      // bytes (= i8 elems) per K-tile
#define NT (K_IN / BK)             // 64 K-tiles
#define RING_STRIDE 32768          // A 16 KiB + B 16 KiB per ring slot
#define LDS_BYTES (2 * RING_STRIDE)  // 64 KiB ring-2 -> 2 blocks/CU

// -------------------------------------------------------------------------
// Pack both int32-carrier tensors into int8 in one dispatch. (~38 us,
// BW-bound: 240 MB @ ~6.3 TB/s)
// -------------------------------------------------------------------------
__device__ __forceinline__ int pack4(int4 a) {
    return (a.x & 255) | ((a.y & 255) << 8) | ((a.z & 255) << 16) | ((a.w & 255) << 24);
}

__global__ __launch_bounds__(256) void pack_both(
    const int4* __restrict__ x, const int4* __restrict__ w,
    int* __restrict__ dA, int* __restrict__ dB, int n4x, int n4w)
{
    int i = blockIdx.x * blockDim.x + threadIdx.x;
    if (i < n4x) {
        dA[i] = pack4(x[i]);
    } else {
        int j = i - n4x;
        if (j < n4w) dB[j] = pack4(w[j]);
    }
}

// -------------------------------------------------------------------------
// i8 GEMM, 256x256 tile, BK=64, 8 waves (2Mx4N), wave = 128x64 as 4x2 of
// mfma_i32_32x32x32_i8.
//
// R6 structure change: RING-2 (64 KiB) -> 2 blocks/CU (4 waves/SIMD).
// R3/R5 both measured 2710 cyc/tile == matrix demand (1170) + LDS demand
// (~1536): the EXACT serial sum, zero skew overhead. In-wave reordering
// (R5 register pipeline) could not overlap the pipes because all 8 waves
// of the single resident block are barrier-locked to the same tile phase.
// A second resident block has an independent barrier clock: its waves
// stream LDS while ours burst MFMA and vice versa (m114 mechanism at
// block granularity). Cost: ring-2 needs a full vmcnt(0)+lgkmcnt(0) drain
// per tile (slot t+1 aliases slot t-1); the lgkm drain hides under the
// preceding 8-MFMA burst, the vmcnt drain is covered by the other block.
// Discriminator: if time stays ~145 us, DS-return and MFMA serialize at
// the CU port level (H2) -> next step is removing A from LDS entirely.
// SQ_LDS_BANK_CONFLICT = 12.0/gload (write-burst fixed cost, invariant
// across 3 read-swizzle variants) -> reads are conflict-free; ignore it.
// -------------------------------------------------------------------------
__global__ __launch_bounds__(512, 4) void gemm_i8_kernel(
    const char* __restrict__ A8,      // [M][K] int8 row-major
    const char* __restrict__ B8,      // [N][K] int8 row-major
    const float* __restrict__ scale_ptr,
    float* __restrict__ out)          // [M][N] float + 1 scalar at end
{
    extern __shared__ char lds[];     // 2 ring slots: [A 16K | B 16K] each

    const int tid  = threadIdx.x;
    const int wave = tid >> 6;        // 0..7
    const int lane = tid & 63;

    // ---- bijective XCD swizzle of the 512-block grid (512 % 8 == 0).
    int wg = (blockIdx.x & 7) * 64 + (blockIdx.x >> 3);
    const int bx = wg >> 5;           // 0..15 (N tiles)
    const int by = wg & 31;           // 0..31 (M tiles)
    const int bm = by * BM;
    const int bn = bx * BN;

    const int wr = wave >> 2;         // 0..1
    const int wc = wave & 3;          // 0..3
    const int wm = wr * 128;          // wave row offset in tile
    const int wn = wc * 64;           // wave col offset in tile

    v16i acc[4][2];
#pragma unroll
    for (int mi = 0; mi < 4; ++mi)
#pragma unroll
        for (int nj = 0; nj < 2; ++nj)
#pragma unroll
            for (int r = 0; r < 16; ++r)
                acc[mi][nj][r] = 0;

    // ---- staging geometry: wave-load = 64 lanes x 16 B = 16 rows of 64 B.
    // Wave stages rows [wave*32, wave*32+32) of A and of B (2 loads each).
    // Source granule pre-swizzled (gload_lds dest is linear lane*16):
    // f(row) = ((row>>1)&3) ^ ((row>>3)&3), row = r0 + srow.
    const int srow = lane >> 2;                                   // 0..15

    const char* gA[2]; const char* gB[2];
    int ldsAoff[2], ldsBoff[2];
#pragma unroll
    for (int q = 0; q < 2; ++q) {
        const int r0  = wave * 32 + q * 16;
        const int f   = ((srow >> 1) & 3) ^ ((srow >> 3) & 1) ^ (q << 1);
        const int sgr = (lane & 3) ^ f;                // swizzled src granule
        gA[q] = A8 + (size_t)(bm + r0 + srow) * K_IN + sgr * 16;
        gB[q] = B8 + (size_t)(bn + r0 + srow) * K_IN + sgr * 16;
        ldsAoff[q] = r0 * 64;              // A at slot offset 0
        ldsBoff[q] = 16384 + r0 * 64;      // B at slot offset 16 KiB
    }

#define ISSUE(tile, q) do {                                                  \
        char* _rb = lds + ((tile) & 1) * RING_STRIDE;                        \
        const int _k0 = (tile) * BK;                                         \
        __builtin_amdgcn_global_load_lds(                                    \
            (const __attribute__((address_space(1))) void*)(gA[q] + _k0),    \
            (__attribute__((address_space(3))) void*)(_rb + ldsAoff[q]),     \
            16, 0, 0);                                                       \
        __builtin_amdgcn_global_load_lds(                                    \
            (const __attribute__((address_space(1))) void*)(gB[q] + _k0),    \
            (__attribute__((address_space(3))) void*)(_rb + ldsBoff[q]),     \
            16, 0, 0);                                                       \
    } while (0)

    // ---- fragment geometry (32x32x32 i8): lane reads 16 B of row fm at
    // global granule g = kk*2 + fh; stored LDS granule = g ^ f(row).
    const int fm  = lane & 31;
    const int fh  = lane >> 5;                          // 0/1
    const int fsw = ((fm >> 1) & 3) ^ ((fm >> 3) & 3);  // f(row)
    const int g0  = ((0 + fh) ^ fsw) << 4;              // kk=0 byte offset
    const int g1  = ((2 + fh) ^ fsw) << 4;              // kk=1 byte offset
    const int abase = (wm + fm) * 64;                   // + mi*2048
    const int bbase = 16384 + (wn + fm) * 64;           // + nj*2048

    // ---- prologue: tile 0 staged, drained, visible
    ISSUE(0, 0); ISSUE(0, 1);
    asm volatile("s_waitcnt vmcnt(0)" ::: "memory");
    __builtin_amdgcn_s_barrier();

    // set0 <- (tile 0, phase 0)
    v4i a0[4], b0[2], a1[4], b1[2];
#pragma unroll
    for (int mi = 0; mi < 4; ++mi)
        a0[mi] = *(const v4i*)(lds + abase + mi * 2048 + g0);
#pragma unroll
    for (int nj = 0; nj < 2; ++nj)
        b0[nj] = *(const v4i*)(lds + bbase + nj * 2048 + g0);

    for (int t = 0; t < NT; ++t) {
        char* rb = lds + (t & 1) * RING_STRIDE;
        const bool pf = (t + 1 < NT);

        // ---- reads (t, ph1) -> set1, prefetch t+1, then MFMA set0 (t,ph0).
        // set1's 6 reads fly under the MFMA burst (counted lgkmcnt).
#pragma unroll
        for (int mi = 0; mi < 4; ++mi)
            a1[mi] = *(const v4i*)(rb + abase + mi * 2048 + g1);
#pragma unroll
        for (int nj = 0; nj < 2; ++nj)
            b1[nj] = *(const v4i*)(rb + bbase + nj * 2048 + g1);
        if (pf) { ISSUE(t + 1, 0); ISSUE(t + 1, 1); }   // 4 gloads, ~1 tile early
        __builtin_amdgcn_sched_barrier(0);   // pin reads above MFMA cluster
        __builtin_amdgcn_s_setprio(1);
#pragma unroll
        for (int mi = 0; mi < 4; ++mi)
#pragma unroll
            for (int nj = 0; nj < 2; ++nj)
                acc[mi][nj] = __builtin_amdgcn_mfma_i32_32x32x32_i8(
                    a0[mi], b0[nj], acc[mi][nj], 0, 0, 0);
        __builtin_amdgcn_s_setprio(0);

        // ---- tile boundary: full drain + ONE barrier.
        // vmcnt(0): own t+1 gloads landed. lgkmcnt(0): own set1 ds_reads
        // retired (ring-2: slot t+1 aliases slot t-1, so no wave may carry
        // outstanding reads past the barrier). Both hide under the 8-MFMA
        // burst / the co-resident block.
        asm volatile("s_waitcnt vmcnt(0) lgkmcnt(0)" ::: "memory");
        __builtin_amdgcn_s_barrier();

        // ---- reads (t+1, ph0) -> set0, then MFMA on set1 (t, ph1).
        if (pf) {
            char* rn = lds + ((t + 1) & 1) * RING_STRIDE;
#pragma unroll
            for (int mi = 0; mi < 4; ++mi)
                a0[mi] = *(const v4i*)(rn + abase + mi * 2048 + g0);
#pragma unroll
            for (int nj = 0; nj < 2; ++nj)
                b0[nj] = *(const v4i*)(rn + bbase + nj * 2048 + g0);
        }
        __builtin_amdgcn_sched_barrier(0);   // pin reads above MFMA cluster
        __builtin_amdgcn_s_setprio(1);
#pragma unroll
        for (int mi = 0; mi < 4; ++mi)
#pragma unroll
            for (int nj = 0; nj < 2; ++nj)
                acc[mi][nj] = __builtin_amdgcn_mfma_i32_32x32x32_i8(
                    a1[mi], b1[nj], acc[mi][nj], 0, 0, 0);
        __builtin_amdgcn_s_setprio(0);
    }
#undef ISSUE

    // ---- epilogue: y = clip(rint(acc * scale), -128, 127) as float
    // 32x32 C/D layout: col = lane&31, row = (reg&3) + 8*(reg>>2) + 4*(lane>>5)
    const float s     = scale_ptr[0];
    const float scale = (s * 0.1f) / 0.1f;   // match ref op order

#pragma unroll
    for (int mi = 0; mi < 4; ++mi) {
#pragma unroll
        for (int nj = 0; nj < 2; ++nj) {
#pragma unroll
            for (int r = 0; r < 16; ++r) {
                int row = bm + wm + mi * 32 + (r & 3) + 8 * (r >> 2) + 4 * fh;
                int col = bn + wn + nj * 32 + fm;
                float y = (float)acc[mi][nj][r] * scale;
                y = rintf(y);
                y = fminf(fmaxf(y, -128.0f), 127.0f);
                out[(size_t)row * N_OUT + col] = y;
            }
        }
    }

    if (bm == 0 && bn == 0 && tid == 0)
        out[(size_t)M_TOK * N_OUT] = 0.1f;
}

// -------------------------------------------------------------------------
extern "C" void kernel_launch(void* const* d_in, const int* in_sizes, int n_in,
                              void* d_out, int out_size, void* d_ws, size_t ws_size,
                              hipStream_t stream)
{
    const int*   x_q     = (const int*)d_in[0];   // [8192*4096] int32 carriers
    const int*   w_q     = (const int*)d_in[1];   // [4096*4096] int32 carriers
    const float* scale_x = (const float*)d_in[2]; // 1 element
    float* out = (float*)d_out;

    char* A8 = (char*)d_ws;                              // 32 MB
    char* B8 = (char*)d_ws + (size_t)M_TOK * K_IN;       // 16 MB

    const int n4x = (M_TOK * K_IN) / 4;   // 8388608
    const int n4w = (N_OUT * K_IN) / 4;   // 4194304

    // one-time: allow 64 KiB dynamic LDS (host-side attribute, not a
    // stream op -> graph-capture safe)
    static bool once = []{
        hipFuncSetAttribute(reinterpret_cast<const void*>(gemm_i8_kernel),
                            hipFuncAttributeMaxDynamicSharedMemorySize,
                            LDS_BYTES);
        return true;
    }();
    (void)once;

    pack_both<<<(n4x + n4w) / 256, 256, 0, stream>>>(
        (const int4*)x_q, (const int4*)w_q, (int*)A8, (int*)B8, n4x, n4w);

    // 512 blocks (16 N-tiles x 32 M-tiles), 512 threads, 64 KiB LDS
    gemm_i8_kernel<<<512, 512, LDS_BYTES, stream>>>(A8, B8, scale_x, out);
}

// Round 7
// 424.443 us; speedup vs baseline: 7.3607x; 7.3607x over previous
//
#include <hip/hip_runtime.h>
#include <stdint.h>

typedef int v4i  __attribute__((ext_vector_type(4)));
typedef int v16i __attribute__((ext_vector_type(16)));

#define M_TOK 8192
#define N_OUT 4096
#define K_IN  4096

#define BM 256
#define BN 128
#define BK 64                      // bytes (= i8 elems) per K-tile
#define NT (K_IN / BK)             // 64 K-tiles
#define SLOT 24576                 // A 16 KiB + B 8 KiB per ring slot
#define LDS_BYTES (3 * SLOT)       // 72 KiB ring-3 -> 2 blocks/CU

// -------------------------------------------------------------------------
// Pack both int32-carrier tensors into int8 in one dispatch. (~38 us,
// BW-bound: 240 MB @ ~6.3 TB/s)
// -------------------------------------------------------------------------
__device__ __forceinline__ int pack4(int4 a) {
    return (a.x & 255) | ((a.y & 255) << 8) | ((a.z & 255) << 16) | ((a.w & 255) << 24);
}

__global__ __launch_bounds__(256) void pack_both(
    const int4* __restrict__ x, const int4* __restrict__ w,
    int* __restrict__ dA, int* __restrict__ dB, int n4x, int n4w)
{
    int i = blockIdx.x * blockDim.x + threadIdx.x;
    if (i < n4x) {
        dA[i] = pack4(x[i]);
    } else {
        int j = i - n4x;
        if (j < n4w) dB[j] = pack4(w[j]);
    }
}

// -------------------------------------------------------------------------
// i8 GEMM, R7: 256x128 tile, 4 waves (2Mx2N), wave = 128x64 as 4x2 of
// mfma_i32_32x32x32_i8 (128 acc VGPR). TWO blocks per CU (the H1 test):
// R3/R5 measured 2710 cyc/tile == matrix (1170) + LDS (1536) EXACTLY --
// zero pipe overlap; in-wave pipelining (R5) didn't create any. All 8
// waves of one block are barrier-locked to the same tile, so read-bursts
// and MFMA-bursts alternate CU-wide. Two co-resident blocks have
// independent barrier clocks -> one block's LDS phase fills the other's
// MFMA phase. Residency: ~210 VGPR @ launch_bounds(256,2) (cap 256;
// R6 LESSON: 2nd arg divides the 512-reg/SIMD pool -- (512,4) capped at
// 128 < acc alone and spilled acc to scratch, 15 GB HBM traffic, 2.9 ms)
// + 72 KiB LDS (2x72 = 144 <= 160).
// Ring-3, prefetch distance 2, counted vmcnt(6); lgkmcnt(0) before the
// single per-tile barrier closes the cross-wave ring-3 race (a wave one
// tile ahead issues gloads into slot (t+3)%3 == t%3 while a slow wave's
// pre-barrier reads of slot t%3 could still be queued).
// SQ_LDS_BANK_CONFLICT = 12.0/gload (write-burst fixed cost, invariant
// across 3 read-swizzle variants) -> reads are conflict-free; ignore it.
// -------------------------------------------------------------------------
__global__ __launch_bounds__(256, 2) void gemm_i8_kernel(
    const char* __restrict__ A8,      // [M][K] int8 row-major
    const char* __restrict__ B8,      // [N][K] int8 row-major
    const float* __restrict__ scale_ptr,
    float* __restrict__ out)          // [M][N] float + 1 scalar at end
{
    extern __shared__ char lds[];     // 3 ring slots: [A 16K | B 8K] each

    const int tid  = threadIdx.x;
    const int wave = tid >> 6;        // 0..3
    const int lane = tid & 63;

    // ---- bijective XCD swizzle of the 1024-block grid (1024 % 8 == 0).
    // Consecutive swizzled ids share bx -> share the 512 KB B panel in L2.
    int wg = (blockIdx.x & 7) * 128 + (blockIdx.x >> 3);
    const int bx = wg >> 5;           // 0..31 (N tiles)
    const int by = wg & 31;           // 0..31 (M tiles)
    const int bm = by * BM;
    const int bn = bx * BN;

    const int wr = wave >> 1;         // 0..1
    const int wc = wave & 1;          // 0..1
    const int wm = wr * 128;          // wave row offset in tile
    const int wn = wc * 64;           // wave col offset in tile

    v16i acc[4][2];
#pragma unroll
    for (int mi = 0; mi < 4; ++mi)
#pragma unroll
        for (int nj = 0; nj < 2; ++nj)
#pragma unroll
            for (int r = 0; r < 16; ++r)
                acc[mi][nj][r] = 0;

    // ---- staging geometry: wave-load = 64 lanes x 16 B = 16 rows of 64 B.
    // Wave stages A rows [wave*64, +64) (4 loads) and B rows [wave*32, +32)
    // (2 loads). Source granule pre-swizzled (gload_lds dest is linear
    // lane*16): f(row) = ((row>>1)&3) ^ ((row>>3)&3); row = r0 + srow with
    // r0 a multiple of 16 -> bit4 of row = (r0>>4)&1 = q&1 for both A and B.
    const int srow = lane >> 2;                                   // 0..15
    const int fbase = ((srow >> 1) & 3) ^ ((srow >> 3) & 1);

    const char* gA[4]; const char* gB[2];
    int ldsAoff[4], ldsBoff[2];
#pragma unroll
    for (int q = 0; q < 4; ++q) {
        const int r0  = wave * 64 + q * 16;
        const int sgr = (lane & 3) ^ fbase ^ ((q & 1) << 1);
        gA[q] = A8 + (size_t)(bm + r0 + srow) * K_IN + sgr * 16;
        ldsAoff[q] = r0 * 64;              // A region at slot offset 0
    }
#pragma unroll
    for (int q = 0; q < 2; ++q) {
        const int r0  = wave * 32 + q * 16;
        const int sgr = (lane & 3) ^ fbase ^ ((q & 1) << 1);
        gB[q] = B8 + (size_t)(bn + r0 + srow) * K_IN + sgr * 16;
        ldsBoff[q] = 16384 + r0 * 64;      // B region at slot offset 16 KiB
    }

#define ISSUE(tile) do {                                                     \
        char* _rb = lds + ((tile) % 3) * SLOT;                               \
        const int _k0 = (tile) * BK;                                         \
        _Pragma("unroll")                                                    \
        for (int _q = 0; _q < 4; ++_q)                                       \
            __builtin_amdgcn_global_load_lds(                                \
                (const __attribute__((address_space(1))) void*)(gA[_q]+_k0), \
                (__attribute__((address_space(3))) void*)(_rb+ldsAoff[_q]),  \
                16, 0, 0);                                                   \
        _Pragma("unroll")                                                    \
        for (int _q = 0; _q < 2; ++_q)                                       \
            __builtin_amdgcn_global_load_lds(                                \
                (const __attribute__((address_space(1))) void*)(gB[_q]+_k0), \
                (__attribute__((address_space(3))) void*)(_rb+ldsBoff[_q]),  \
                16, 0, 0);                                                   \
    } while (0)

    // ---- fragment geometry (32x32x32 i8): lane reads 16 B of row fm at
    // global granule g = kk*2 + fh; stored LDS granule = g ^ f(row);
    // row === fm (mod 32) on both A and B paths.
    const int fm  = lane & 31;
    const int fh  = lane >> 5;                          // 0/1
    const int fsw = ((fm >> 1) & 3) ^ ((fm >> 3) & 3);  // f(row)
    const int g0  = ((0 + fh) ^ fsw) << 4;              // kk=0 byte offset
    const int g1  = ((2 + fh) ^ fsw) << 4;              // kk=1 byte offset
    const int abase = (wm + fm) * 64;                   // + mi*2048
    const int bbase = 16384 + (wn + fm) * 64;           // + nj*2048

    // ---- prologue: tiles 0,1 in flight (12 issues/wave), tile 0 landed
    ISSUE(0); ISSUE(1);
    asm volatile("s_waitcnt vmcnt(6)" ::: "memory");
    __builtin_amdgcn_s_barrier();

    // set0 <- (tile 0, phase 0)
    v4i a0[4], b0[2], a1[4], b1[2];
#pragma unroll
    for (int mi = 0; mi < 4; ++mi)
        a0[mi] = *(const v4i*)(lds + abase + mi * 2048 + g0);
#pragma unroll
    for (int nj = 0; nj < 2; ++nj)
        b0[nj] = *(const v4i*)(lds + bbase + nj * 2048 + g0);

    for (int t = 0; t < NT; ++t) {
        char* rb = lds + (t % 3) * SLOT;
        const bool pf = (t + 2 < NT);

        // ---- reads (t, ph1) -> set1, prefetch t+2, MFMA set0 (t, ph0).
        // set1's 6 reads fly under the MFMA burst (counted lgkmcnt).
#pragma unroll
        for (int mi = 0; mi < 4; ++mi)
            a1[mi] = *(const v4i*)(rb + abase + mi * 2048 + g1);
#pragma unroll
        for (int nj = 0; nj < 2; ++nj)
            b1[nj] = *(const v4i*)(rb + bbase + nj * 2048 + g1);
        if (pf) ISSUE(t + 2);
        __builtin_amdgcn_sched_barrier(0);   // pin reads above MFMA cluster
        __builtin_amdgcn_s_setprio(1);
#pragma unroll
        for (int mi = 0; mi < 4; ++mi)
#pragma unroll
            for (int nj = 0; nj < 2; ++nj)
                acc[mi][nj] = __builtin_amdgcn_mfma_i32_32x32x32_i8(
                    a0[mi], b0[nj], acc[mi][nj], 0, 0, 0);
        __builtin_amdgcn_s_setprio(0);

        // ---- tile boundary. vmcnt(6): own t+1 gloads landed (t+2's six
        // may fly). lgkmcnt(0): own set1 reads of slot t%3 retired before
        // the barrier -- a wave one tile ahead gloads into slot (t+3)%3 ==
        // t%3, so reads must not be outstanding across the barrier.
        if (pf) asm volatile("s_waitcnt vmcnt(6)" ::: "memory");
        else    asm volatile("s_waitcnt vmcnt(0)" ::: "memory");
        asm volatile("s_waitcnt lgkmcnt(0)" ::: "memory");
        __builtin_amdgcn_sched_barrier(0);
        __builtin_amdgcn_s_barrier();

        // ---- reads (t+1, ph0) -> set0, then MFMA on set1 (t, ph1).
        if (t + 1 < NT) {
            char* rn = lds + ((t + 1) % 3) * SLOT;
#pragma unroll
            for (int mi = 0; mi < 4; ++mi)
                a0[mi] = *(const v4i*)(rn + abase + mi * 2048 + g0);
#pragma unroll
            for (int nj = 0; nj < 2; ++nj)
                b0[nj] = *(const v4i*)(rn + bbase + nj * 2048 + g0);
        }
        __builtin_amdgcn_sched_barrier(0);   // pin reads above MFMA cluster
        __builtin_amdgcn_s_setprio(1);
#pragma unroll
        for (int mi = 0; mi < 4; ++mi)
#pragma unroll
            for (int nj = 0; nj < 2; ++nj)
                acc[mi][nj] = __builtin_amdgcn_mfma_i32_32x32x32_i8(
                    a1[mi], b1[nj], acc[mi][nj], 0, 0, 0);
        __builtin_amdgcn_s_setprio(0);
    }
#undef ISSUE

    // ---- epilogue: y = clip(rint(acc * scale), -128, 127) as float
    // 32x32 C/D layout: col = lane&31, row = (reg&3) + 8*(reg>>2) + 4*(lane>>5)
    const float s     = scale_ptr[0];
    const float scale = (s * 0.1f) / 0.1f;   // match ref op order

#pragma unroll
    for (int mi = 0; mi < 4; ++mi) {
#pragma unroll
        for (int nj = 0; nj < 2; ++nj) {
#pragma unroll
            for (int r = 0; r < 16; ++r) {
                int row = bm + wm + mi * 32 + (r & 3) + 8 * (r >> 2) + 4 * fh;
                int col = bn + wn + nj * 32 + fm;
                float y = (float)acc[mi][nj][r] * scale;
                y = rintf(y);
                y = fminf(fmaxf(y, -128.0f), 127.0f);
                out[(size_t)row * N_OUT + col] = y;
            }
        }
    }

    if (bm == 0 && bn == 0 && tid == 0)
        out[(size_t)M_TOK * N_OUT] = 0.1f;
}

// -------------------------------------------------------------------------
extern "C" void kernel_launch(void* const* d_in, const int* in_sizes, int n_in,
                              void* d_out, int out_size, void* d_ws, size_t ws_size,
                              hipStream_t stream)
{
    const int*   x_q     = (const int*)d_in[0];   // [8192*4096] int32 carriers
    const int*   w_q     = (const int*)d_in[1];   // [4096*4096] int32 carriers
    const float* scale_x = (const float*)d_in[2]; // 1 element
    float* out = (float*)d_out;

    char* A8 = (char*)d_ws;                              // 32 MB
    char* B8 = (char*)d_ws + (size_t)M_TOK * K_IN;       // 16 MB

    const int n4x = (M_TOK * K_IN) / 4;   // 8388608
    const int n4w = (N_OUT * K_IN) / 4;   // 4194304

    // one-time: allow 72 KiB dynamic LDS (host-side attribute, not a
    // stream op -> graph-capture safe)
    static bool once = []{
        hipFuncSetAttribute(reinterpret_cast<const void*>(gemm_i8_kernel),
                            hipFuncAttributeMaxDynamicSharedMemorySize,
                            LDS_BYTES);
        return true;
    }();
    (void)once;

    pack_both<<<(n4x + n4w) / 256, 256, 0, stream>>>(
        (const int4*)x_q, (const int4*)w_q, (int*)A8, (int*)B8, n4x, n4w);

    // 1024 blocks (32 N-tiles x 32 M-tiles), 256 threads, 72 KiB LDS
    gemm_i8_kernel<<<1024, 256, LDS_BYTES, stream>>>(A8, B8, scale_x, out);
}

// Round 8
// 391.985 us; speedup vs baseline: 7.9702x; 1.0828x over previous
//
#include <hip/hip_runtime.h>
#include <stdint.h>

typedef int v4i  __attribute__((ext_vector_type(4)));
typedef int v16i __attribute__((ext_vector_type(16)));

#define M_TOK 8192
#define N_OUT 4096
#define K_IN  4096

#define BM 256
#define BN 256
#define BK 64                      // bytes (= i8 elems) per K-tile
#define NT (K_IN / BK)             // 64 K-tiles
#define RING_STRIDE 32768          // A 16 KiB + B 16 KiB per ring slot
#define LDS_BYTES (4 * RING_STRIDE)  // 128 KiB, ring of 4 (depth-2 prefetch)

// sched_group_barrier masks (LLVM SchedGroupMask, verified m137)
#define SGB __builtin_amdgcn_sched_group_barrier
#define SG_MFMA 0x8
#define SG_VMEM 0x20
#define SG_DSRD 0x100

// -------------------------------------------------------------------------
// Pack both int32-carrier tensors into int8 in one dispatch. (~38 us,
// BW-bound: 240 MB @ ~6.3 TB/s)
// -------------------------------------------------------------------------
__device__ __forceinline__ int pack4(int4 a) {
    return (a.x & 255) | ((a.y & 255) << 8) | ((a.z & 255) << 16) | ((a.w & 255) << 24);
}

__global__ __launch_bounds__(256) void pack_both(
    const int4* __restrict__ x, const int4* __restrict__ w,
    int* __restrict__ dA, int* __restrict__ dB, int n4x, int n4w)
{
    int i = blockIdx.x * blockDim.x + threadIdx.x;
    if (i < n4x) {
        dA[i] = pack4(x[i]);
    } else {
        int j = i - n4x;
        if (j < n4w) dB[j] = pack4(w[j]);
    }
}

// -------------------------------------------------------------------------
// i8 GEMM, 256x256 tile, BK=64, 8 waves (2Mx4N), wave = 128x64 as 4x2 of
// mfma_i32_32x32x32_i8. Ring-4 LDS (128 KiB), global_load_lds staging,
// counted vmcnt(8) once per K-tile, ONE barrier per K-tile. (R3/R5 base,
// best measured: 145 us gemm.)
//
// R8 structure change: 1:1 DS_READ/MFMA INTERLEAVE via sched_group_barrier.
// R3/R5/R7 all measured per-tile time == LDS-pipe demand (~1536 cyc CU-wide
// incl. gload write-bursts) + MFMA wall (~1171 cyc; 32 MFMA/SIMD x 36.6
// cyc on the per-SIMD matrix pipe) -- the SUM, zero overlap. Cause: the
// back-to-back MFMA cluster pins the wave at issue (~36 cyc per 32x32
// MFMA accepted), so the wave issues NO ds_reads during the ~293-cyc
// cluster drain; with both waves/SIMD barrier-locked at the same program
// point, read-bursts and MFMA-bursts alternate CU-wide (serial sum).
// R5's reads-before-cluster couldn't fix it (sched_barrier(0) pinned reads
// OUTSIDE the cluster). Fix = AITER/m201's interleave: emit
// R,M,R,M,...,V,M so each MFMA-issue stall absorbs one LDS/VMEM issue;
// 8 MFMAs hide 6 reads + 2 gloads -> LDS streams under the matrix pipe.
// setprio dropped: lockstep schedule gives it nothing to arbitrate (m190)
// and it must not fence the interleave. Loop body branch-free (clamped
// prefetch source into the dead ring slot (t+3)&3 == (t-1)&3; never read
// again for t >= NT-3) so each phase is one scheduling region.
// SQ_LDS_BANK_CONFLICT = 12.0/gload (write-burst fixed cost, invariant
// across 3 read-swizzle variants) -> reads are conflict-free; ignore it.
// -------------------------------------------------------------------------
__global__ __launch_bounds__(512, 2) void gemm_i8_kernel(
    const char* __restrict__ A8,      // [M][K] int8 row-major
    const char* __restrict__ B8,      // [N][K] int8 row-major
    const float* __restrict__ scale_ptr,
    float* __restrict__ out)          // [M][N] float + 1 scalar at end
{
    extern __shared__ char lds[];     // 4 ring slots: [A 16K | B 16K] each

    const int tid  = threadIdx.x;
    const int wave = tid >> 6;        // 0..7
    const int lane = tid & 63;

    // ---- bijective XCD swizzle of the 512-block grid (512 % 8 == 0).
    int wg = (blockIdx.x & 7) * 64 + (blockIdx.x >> 3);
    const int bx = wg >> 5;           // 0..15 (N tiles)
    const int by = wg & 31;           // 0..31 (M tiles)
    const int bm = by * BM;
    const int bn = bx * BN;

    const int wr = wave >> 2;         // 0..1
    const int wc = wave & 3;          // 0..3
    const int wm = wr * 128;          // wave row offset in tile
    const int wn = wc * 64;           // wave col offset in tile

    v16i acc[4][2];
#pragma unroll
    for (int mi = 0; mi < 4; ++mi)
#pragma unroll
        for (int nj = 0; nj < 2; ++nj)
#pragma unroll
            for (int r = 0; r < 16; ++r)
                acc[mi][nj][r] = 0;

    // ---- staging geometry: wave-load = 64 lanes x 16 B = 16 rows of 64 B.
    // Wave stages rows [wave*32, wave*32+32) of A and of B (2 loads each).
    // Source granule pre-swizzled (gload_lds dest is linear lane*16):
    // f(row) = ((row>>1)&3) ^ ((row>>3)&3), row = r0 + srow.
    const int srow = lane >> 2;                                   // 0..15

    const char* gA[2]; const char* gB[2];
    int ldsAoff[2], ldsBoff[2];
#pragma unroll
    for (int q = 0; q < 2; ++q) {
        const int r0  = wave * 32 + q * 16;
        const int f   = ((srow >> 1) & 3) ^ ((srow >> 3) & 1) ^ (q << 1);
        const int sgr = (lane & 3) ^ f;                // swizzled src granule
        gA[q] = A8 + (size_t)(bm + r0 + srow) * K_IN + sgr * 16;
        gB[q] = B8 + (size_t)(bn + r0 + srow) * K_IN + sgr * 16;
        ldsAoff[q] = r0 * 64;              // A at slot offset 0
        ldsBoff[q] = 16384 + r0 * 64;      // B at slot offset 16 KiB
    }

    // ISSUE: dest slot from (tile)&3, source K clamped to a valid tile.
    // For tile >= NT the dest slot is dead (never read again), so staging
    // stale data there is harmless; keeps the loop body branch-free.
#define ISSUE(tile, q) do {                                                  \
        char* _rb = lds + ((tile) & 3) * RING_STRIDE;                        \
        const int _src = ((tile) < NT) ? (tile) : (NT - 1);                  \
        const int _k0 = _src * BK;                                           \
        __builtin_amdgcn_global_load_lds(                                    \
            (const __attribute__((address_space(1))) void*)(gA[q] + _k0),    \
            (__attribute__((address_space(3))) void*)(_rb + ldsAoff[q]),     \
            16, 0, 0);                                                       \
        __builtin_amdgcn_global_load_lds(                                    \
            (const __attribute__((address_space(1))) void*)(gB[q] + _k0),    \
            (__attribute__((address_space(3))) void*)(_rb + ldsBoff[q]),     \
            16, 0, 0);                                                       \
    } while (0)

    // ---- fragment geometry (32x32x32 i8): lane reads 16 B of row fm at
    // global granule g = kk*2 + fh; stored LDS granule = g ^ f(row).
    const int fm  = lane & 31;
    const int fh  = lane >> 5;                          // 0/1
    const int fsw = ((fm >> 1) & 3) ^ ((fm >> 3) & 3);  // f(row)
    const int g0  = ((0 + fh) ^ fsw) << 4;              // kk=0 byte offset
    const int g1  = ((2 + fh) ^ fsw) << 4;              // kk=1 byte offset
    const int abase = (wm + fm) * 64;                   // + mi*2048
    const int bbase = 16384 + (wn + fm) * 64;           // + nj*2048

    // ---- prologue: tiles 0,1,2 in flight (12 issues/wave)
    ISSUE(0, 0); ISSUE(0, 1);
    ISSUE(1, 0); ISSUE(1, 1);
    ISSUE(2, 0); ISSUE(2, 1);
    asm volatile("s_waitcnt vmcnt(8)" ::: "memory");   // tile 0 landed
    __builtin_amdgcn_s_barrier();

    // set0 <- (tile 0, phase 0)
    v4i a0[4], b0[2], a1[4], b1[2];
#pragma unroll
    for (int mi = 0; mi < 4; ++mi)
        a0[mi] = *(const v4i*)(lds + abase + mi * 2048 + g0);
#pragma unroll
    for (int nj = 0; nj < 2; ++nj)
        b0[nj] = *(const v4i*)(lds + bbase + nj * 2048 + g0);

    for (int t = 0; t < NT; ++t) {
        char* rb = lds + (t & 3) * RING_STRIDE;
        char* rn = lds + ((t + 1) & 3) * RING_STRIDE;

        // ======== phase A: reads (t,ph1)->set1, 2 gloads, MFMA set0 ======
#pragma unroll
        for (int mi = 0; mi < 4; ++mi)
            a1[mi] = *(const v4i*)(rb + abase + mi * 2048 + g1);
#pragma unroll
        for (int nj = 0; nj < 2; ++nj)
            b1[nj] = *(const v4i*)(rb + bbase + nj * 2048 + g1);
        ISSUE(t + 3, 0);
#pragma unroll
        for (int mi = 0; mi < 4; ++mi)
#pragma unroll
            for (int nj = 0; nj < 2; ++nj)
                acc[mi][nj] = __builtin_amdgcn_mfma_i32_32x32x32_i8(
                    a0[mi], b0[nj], acc[mi][nj], 0, 0, 0);
        // interleave: R,M x6 then V,M x2 -- each MFMA-issue stall absorbs
        // one LDS/VMEM issue so the LDS pipe streams under the matrix pipe.
        SGB(SG_DSRD, 1, 0); SGB(SG_MFMA, 1, 0);
        SGB(SG_DSRD, 1, 0); SGB(SG_MFMA, 1, 0);
        SGB(SG_DSRD, 1, 0); SGB(SG_MFMA, 1, 0);
        SGB(SG_DSRD, 1, 0); SGB(SG_MFMA, 1, 0);
        SGB(SG_DSRD, 1, 0); SGB(SG_MFMA, 1, 0);
        SGB(SG_DSRD, 1, 0); SGB(SG_MFMA, 1, 0);
        SGB(SG_VMEM, 1, 0); SGB(SG_MFMA, 1, 0);
        SGB(SG_VMEM, 1, 0); SGB(SG_MFMA, 1, 0);

        // ---- tile boundary: counted vmcnt (never 0) + ONE barrier
        ISSUE(t + 3, 1);
        asm volatile("s_waitcnt vmcnt(8)" ::: "memory");
        __builtin_amdgcn_s_barrier();

        // ======== phase B: reads (t+1,ph0)->set0, MFMA set1 ==============
        // (at t = NT-1 the reads hit a stale slot; values feed nothing)
#pragma unroll
        for (int mi = 0; mi < 4; ++mi)
            a0[mi] = *(const v4i*)(rn + abase + mi * 2048 + g0);
#pragma unroll
        for (int nj = 0; nj < 2; ++nj)
            b0[nj] = *(const v4i*)(rn + bbase + nj * 2048 + g0);
#pragma unroll
        for (int mi = 0; mi < 4; ++mi)
#pragma unroll
            for (int nj = 0; nj < 2; ++nj)
                acc[mi][nj] = __builtin_amdgcn_mfma_i32_32x32x32_i8(
                    a1[mi], b1[nj], acc[mi][nj], 0, 0, 0);
        SGB(SG_DSRD, 1, 0); SGB(SG_MFMA, 1, 0);
        SGB(SG_DSRD, 1, 0); SGB(SG_MFMA, 1, 0);
        SGB(SG_DSRD, 1, 0); SGB(SG_MFMA, 1, 0);
        SGB(SG_DSRD, 1, 0); SGB(SG_MFMA, 1, 0);
        SGB(SG_DSRD, 1, 0); SGB(SG_MFMA, 1, 0);
        SGB(SG_DSRD, 1, 0); SGB(SG_MFMA, 1, 0);
        SGB(SG_MFMA, 2, 0);
    }
#undef ISSUE

    // ---- epilogue: y = clip(rint(acc * scale), -128, 127) as float
    // 32x32 C/D layout: col = lane&31, row = (reg&3) + 8*(reg>>2) + 4*(lane>>5)
    const float s     = scale_ptr[0];
    const float scale = (s * 0.1f) / 0.1f;   // match ref op order

#pragma unroll
    for (int mi = 0; mi < 4; ++mi) {
#pragma unroll
        for (int nj = 0; nj < 2; ++nj) {
#pragma unroll
            for (int r = 0; r < 16; ++r) {
                int row = bm + wm + mi * 32 + (r & 3) + 8 * (r >> 2) + 4 * fh;
                int col = bn + wn + nj * 32 + fm;
                float y = (float)acc[mi][nj][r] * scale;
                y = rintf(y);
                y = fminf(fmaxf(y, -128.0f), 127.0f);
                out[(size_t)row * N_OUT + col] = y;
            }
        }
    }

    if (bm == 0 && bn == 0 && tid == 0)
        out[(size_t)M_TOK * N_OUT] = 0.1f;
}

// -------------------------------------------------------------------------
extern "C" void kernel_launch(void* const* d_in, const int* in_sizes, int n_in,
                              void* d_out, int out_size, void* d_ws, size_t ws_size,
                              hipStream_t stream)
{
    const int*   x_q     = (const int*)d_in[0];   // [8192*4096] int32 carriers
    const int*   w_q     = (const int*)d_in[1];   // [4096*4096] int32 carriers
    const float* scale_x = (const float*)d_in[2]; // 1 element
    float* out = (float*)d_out;

    char* A8 = (char*)d_ws;                              // 32 MB
    char* B8 = (char*)d_ws + (size_t)M_TOK * K_IN;       // 16 MB

    const int n4x = (M_TOK * K_IN) / 4;   // 8388608
    const int n4w = (N_OUT * K_IN) / 4;   // 4194304

    // one-time: allow 128 KiB dynamic LDS (host-side attribute, not a
    // stream op -> graph-capture safe)
    static bool once = []{
        hipFuncSetAttribute(reinterpret_cast<const void*>(gemm_i8_kernel),
                            hipFuncAttributeMaxDynamicSharedMemorySize,
                            LDS_BYTES);
        return true;
    }();
    (void)once;

    pack_both<<<(n4x + n4w) / 256, 256, 0, stream>>>(
        (const int4*)x_q, (const int4*)w_q, (int*)A8, (int*)B8, n4x, n4w);

    // 512 blocks (16 N-tiles x 32 M-tiles), 512 threads, 128 KiB LDS
    gemm_i8_kernel<<<512, 512, LDS_BYTES, stream>>>(A8, B8, scale_x, out);
}